// Round 8
// baseline (354.571 us; speedup 1.0000x reference)
//
#include <hip/hip_runtime.h>

#define EMBED   256
#define NGRAPH  256
#define NW      16           // waves per block
#define BLOCK   (NW * 64)    // 1024 threads
#define LD4     (EMBED / 4)  // row stride in f32x4 units

typedef float f32x4 __attribute__((ext_vector_type(4)));

// ---------------------------------------------------------------------------
// One block per graph (batch sorted -> contiguous node range via binary
// search). Round-8 == round-7 resubmit (round-7 bench died in infra, no
// data). Phase A ONLY change vs round 6: each wave's contiguous chunk is
// split into 4 INDEPENDENT streams (separate base pointers, separate
// accumulators). Theory: VGPR_Count=32 proves the round-6 unroll-16 was
// register-recycled into a single serialized address chain (few loads
// actually outstanding); 4 independent chains force ~4x more loads in
// flight per wave regardless of how the compiler schedules vmcnt waits.
// nt loads kept (isolates the stream-split as the single variable).
// Phases B and C byte-identical to round 6.
// ---------------------------------------------------------------------------
__global__ __launch_bounds__(BLOCK, 4) void fused_kernel(
    const float* __restrict__ x, const int* __restrict__ batch,
    const float* __restrict__ in_w, const float* __restrict__ in_b,
    const float* __restrict__ out_w, const float* __restrict__ out_b,
    float* __restrict__ out, int nNodes) {
  const int g = blockIdx.x;
  const int t = threadIdx.x;
  const int q  = t >> 6;   // wave id 0..15
  const int c4 = t & 63;   // float4 column 0..63

  // node range [n0, n1) for graph g
  int n0, n1;
  { int a = 0, b = nNodes;
    while (a < b) { int m = (a + b) >> 1; (batch[m] < g) ? (a = m + 1) : (b = m); }
    n0 = a; }
  { int a = n0, b = nNodes;
    while (a < b) { int m = (a + b) >> 1; (batch[m] <= g) ? (a = m + 1) : (b = m); }
    n1 = a; }
  const int cnt = n1 - n0;

  // ---- A) segment sum: wave q owns contiguous rows [w0, w1);
  //         chunk split into 4 independent streams ----
  const int chunk = (cnt + NW - 1) / NW;
  const int w0 = min(q * chunk, cnt);
  const int w1 = min(w0 + chunk, cnt);
  const int m  = w1 - w0;

  const int len = (m + 3) >> 2;               // stream stride (rows)
  const int l0 = max(0, min(len, m          ));
  const int l1 = max(0, min(len, m - 1 * len));
  const int l2 = max(0, min(len, m - 2 * len));
  const int l3 = max(0, min(len, m - 3 * len));

  const f32x4* xq = (const f32x4*)x + (size_t)(n0 + w0) * LD4 + c4;
  const f32x4* p0 = xq;
  const f32x4* p1 = xq + (size_t)(1 * len) * LD4;
  const f32x4* p2 = xq + (size_t)(2 * len) * LD4;
  const f32x4* p3 = xq + (size_t)(3 * len) * LD4;

  f32x4 b0 = 0.f, b1 = 0.f, b2 = 0.f, b3 = 0.f;
  int j = 0;
  // main loop: 4 streams x unroll-4 = 16 KB issued per iteration per wave,
  // across 4 independent address chains.
  for (; j + 3 < l3; j += 4) {
    f32x4 u0  = __builtin_nontemporal_load(p0 + (size_t)(j + 0) * LD4);
    f32x4 u1  = __builtin_nontemporal_load(p1 + (size_t)(j + 0) * LD4);
    f32x4 u2  = __builtin_nontemporal_load(p2 + (size_t)(j + 0) * LD4);
    f32x4 u3  = __builtin_nontemporal_load(p3 + (size_t)(j + 0) * LD4);
    f32x4 u4  = __builtin_nontemporal_load(p0 + (size_t)(j + 1) * LD4);
    f32x4 u5  = __builtin_nontemporal_load(p1 + (size_t)(j + 1) * LD4);
    f32x4 u6  = __builtin_nontemporal_load(p2 + (size_t)(j + 1) * LD4);
    f32x4 u7  = __builtin_nontemporal_load(p3 + (size_t)(j + 1) * LD4);
    f32x4 u8  = __builtin_nontemporal_load(p0 + (size_t)(j + 2) * LD4);
    f32x4 u9  = __builtin_nontemporal_load(p1 + (size_t)(j + 2) * LD4);
    f32x4 u10 = __builtin_nontemporal_load(p2 + (size_t)(j + 2) * LD4);
    f32x4 u11 = __builtin_nontemporal_load(p3 + (size_t)(j + 2) * LD4);
    f32x4 u12 = __builtin_nontemporal_load(p0 + (size_t)(j + 3) * LD4);
    f32x4 u13 = __builtin_nontemporal_load(p1 + (size_t)(j + 3) * LD4);
    f32x4 u14 = __builtin_nontemporal_load(p2 + (size_t)(j + 3) * LD4);
    f32x4 u15 = __builtin_nontemporal_load(p3 + (size_t)(j + 3) * LD4);
    b0 += u0;  b1 += u1;  b2 += u2;  b3 += u3;
    b0 += u4;  b1 += u5;  b2 += u6;  b3 += u7;
    b0 += u8;  b1 += u9;  b2 += u10; b3 += u11;
    b0 += u12; b1 += u13; b2 += u14; b3 += u15;
  }
  // tails (stream lengths: l0 >= l1 >= l2 >= l3)
  for (int jj = j; jj < l3; ++jj) b3 += __builtin_nontemporal_load(p3 + (size_t)jj * LD4);
  for (int jj = j; jj < l2; ++jj) b2 += __builtin_nontemporal_load(p2 + (size_t)jj * LD4);
  for (int jj = j; jj < l1; ++jj) b1 += __builtin_nontemporal_load(p1 + (size_t)jj * LD4);
  for (int jj = j; jj < l0; ++jj) b0 += __builtin_nontemporal_load(p0 + (size_t)jj * LD4);
  const f32x4 asum = (b0 + b1) + (b2 + b3);

  // ---- cross-wave reduce + mean ----
  __shared__ f32x4 red4[NW][EMBED / 4];    // layout == float [NW][EMBED]
  __shared__ float sg[EMBED];
  __shared__ float sv[EMBED];
  __shared__ float so[EMBED];
  red4[q][c4] = asum;
  __syncthreads();

  const float inv = 1.0f / fmaxf((float)cnt, 1.0f);
  if (t < EMBED) {
    const float* rf = (const float*)red4;
    float s = 0.f;
#pragma unroll
    for (int k = 0; k < NW; ++k) s += rf[k * EMBED + t];
    sg[t] = s * inv;
  }
  __syncthreads();

  // ---- B) matvec 1: v = mean @ Wv^T + bv (thread t -> column t) ----
  if (t < EMBED) {
    float acc = in_b[2 * EMBED + t];
    const float4* wrow = (const float4*)(in_w + (size_t)(2 * EMBED + t) * EMBED);
#pragma unroll 8
    for (int k4 = 0; k4 < EMBED / 4; ++k4) {
      const float4 w = wrow[k4];
      const int k = k4 * 4;
      acc += sg[k] * w.x + sg[k + 1] * w.y + sg[k + 2] * w.z + sg[k + 3] * w.w;
    }
    sv[t] = acc;
  }
  __syncthreads();

  // ---- matvec 2: row = v @ W2^T + b2 ----
  if (t < EMBED) {
    float acc = out_b[t];
    const float4* wrow = (const float4*)(out_w + (size_t)t * EMBED);
#pragma unroll 8
    for (int k4 = 0; k4 < EMBED / 4; ++k4) {
      const float4 w = wrow[k4];
      const int k = k4 * 4;
      acc += sv[k] * w.x + sv[k + 1] * w.y + sv[k + 2] * w.z + sv[k + 3] * w.w;
    }
    so[t] = acc;
  }
  __syncthreads();

  // ---- C) nontemporal broadcast of the graph row to all its nodes ----
  const f32x4 oval = *(const f32x4*)&((const float*)so)[c4 * 4];
  f32x4* op = (f32x4*)out + c4;
  int n = n0 + q;
  for (; n + 3 * NW < n1; n += 4 * NW) {
    __builtin_nontemporal_store(oval, op + (size_t)(n         ) * LD4);
    __builtin_nontemporal_store(oval, op + (size_t)(n + 1 * NW) * LD4);
    __builtin_nontemporal_store(oval, op + (size_t)(n + 2 * NW) * LD4);
    __builtin_nontemporal_store(oval, op + (size_t)(n + 3 * NW) * LD4);
  }
  for (; n < n1; n += NW) {
    __builtin_nontemporal_store(oval, op + (size_t)n * LD4);
  }
}

extern "C" void kernel_launch(void* const* d_in, const int* in_sizes, int n_in,
                              void* d_out, int out_size, void* d_ws, size_t ws_size,
                              hipStream_t stream) {
  const float* x     = (const float*)d_in[0];
  const float* in_w  = (const float*)d_in[1];
  const float* in_b  = (const float*)d_in[2];
  const float* out_w = (const float*)d_in[3];
  const float* out_b = (const float*)d_in[4];
  const int*   batch = (const int*)d_in[5];
  const int nNodes = in_sizes[5];

  fused_kernel<<<NGRAPH, BLOCK, 0, stream>>>(x, batch, in_w, in_b, out_w, out_b,
                                             (float*)d_out, nNodes);
}